// Round 9
// baseline (674.690 us; speedup 1.0000x reference)
//
#include <hip/hip_runtime.h>

// GAT (2-layer) on MI355X — full-CSR + LDS-tiled GEMMs + replicated histograms.
// Closed-form segment softmax: alpha in {+t,-t}; per-src s: p=#pos out-edges,
// deg=out-degree (incl self-loop).
//   w = (flag?1:c) * dinv[s],  dinv = p>0 ? 1/(p+(deg-p)c) : 1/(c*deg).
// edge_index arrives as int32 (harness converts integer inputs).
// R5: per-thread W register arrays spill -> keep W in LDS.
// R6: no __launch_bounds__ -> VGPR cap 64 -> spill; wt[64][64] 64-way conflict.
// R7: (256,2) still capped 128 -> partial spill; (256,1) fixed it (R8).
// R8: hist_k 125us @ 27G atomics/s: 3.4M atomics onto 800KB = 272 ops/line,
//     cross-XCD line ping-pong. Fix: 8-way replication (r=blockIdx&7) +
//     in-place suboff fetch-and-inc for slot claim.
#define EXPC 0.13533528323661270f  // exp(-2*1.0)
#define REP 8

__global__ void zero_i32(int* __restrict__ p, int n) {
  int i = blockIdx.x * blockDim.x + threadIdx.x;
  if (i < n) p[i] = 0;
}

// h[N,64] = (RELU_IN ? relu(x) : x)[N,64] @ W[64,64]^T.
// 64-row tile per block, 256 threads as 16x16, 4x4 register blocking.
template <bool RELU_IN>
__global__ void __launch_bounds__(256, 1)
gemm64_k(const float* __restrict__ x, const float* __restrict__ W,
         float* __restrict__ h, int N) {
  __shared__ float xs[64][68];   // pad 68: conflict-lite
  __shared__ float wt[64][68];   // wt[k][c] = W[c][k]
  const int t = threadIdx.x;
  const int r0 = blockIdx.x * 64;
  for (int i = t; i < 4096; i += 256) {
    int c = i >> 6, k = i & 63;
    wt[k][c] = W[i];
  }
  for (int s = t; s < 1024; s += 256) {  // 64 rows x 16 float4
    int r = s >> 4, c4 = (s & 15) << 2;
    float4 v = make_float4(0.f, 0.f, 0.f, 0.f);
    if (r0 + r < N) {
      v = *(const float4*)(x + (size_t)(r0 + r) * 64 + c4);
      if (RELU_IN) {
        v.x = fmaxf(v.x, 0.f); v.y = fmaxf(v.y, 0.f);
        v.z = fmaxf(v.z, 0.f); v.w = fmaxf(v.w, 0.f);
      }
    }
    *(float4*)(&xs[r][c4]) = v;
  }
  __syncthreads();
  const int ty = t >> 4, tx = t & 15;
  float acc[4][4] = {};
  for (int kk = 0; kk < 64; kk += 4) {
    float4 a[4], w[4];
#pragma unroll
    for (int i = 0; i < 4; i++) a[i] = *(const float4*)(&xs[4 * ty + i][kk]);
#pragma unroll
    for (int m = 0; m < 4; m++) w[m] = *(const float4*)(&wt[kk + m][4 * tx]);
#pragma unroll
    for (int i = 0; i < 4; i++) {
      acc[i][0] = fmaf(a[i].x, w[0].x, fmaf(a[i].y, w[1].x,
                  fmaf(a[i].z, w[2].x, fmaf(a[i].w, w[3].x, acc[i][0]))));
      acc[i][1] = fmaf(a[i].x, w[0].y, fmaf(a[i].y, w[1].y,
                  fmaf(a[i].z, w[2].y, fmaf(a[i].w, w[3].y, acc[i][1]))));
      acc[i][2] = fmaf(a[i].x, w[0].z, fmaf(a[i].y, w[1].z,
                  fmaf(a[i].z, w[2].z, fmaf(a[i].w, w[3].z, acc[i][2]))));
      acc[i][3] = fmaf(a[i].x, w[0].w, fmaf(a[i].y, w[1].w,
                  fmaf(a[i].z, w[2].w, fmaf(a[i].w, w[3].w, acc[i][3]))));
    }
  }
#pragma unroll
  for (int i = 0; i < 4; i++) {
    int row = r0 + 4 * ty + i;
    if (row < N)
      *(float4*)(h + (size_t)row * 64 + 4 * tx) =
          make_float4(acc[i][0], acc[i][1], acc[i][2], acc[i][3]);
  }
}

// h[N,16] = relu(x)[N,64] @ W[16,64]^T.
template <bool RELU_IN>
__global__ void __launch_bounds__(256, 2)
gemm16_k(const float* __restrict__ x, const float* __restrict__ W,
         float* __restrict__ h, int N) {
  __shared__ float xs[64][68];
  __shared__ float wt[64][20];  // wt[k][c] = W[c][k]
  const int t = threadIdx.x;
  const int r0 = blockIdx.x * 64;
  for (int i = t; i < 1024; i += 256) {
    int c = i >> 6, k = i & 63;
    wt[k][c] = W[i];
  }
  for (int s = t; s < 1024; s += 256) {
    int r = s >> 4, c4 = (s & 15) << 2;
    float4 v = make_float4(0.f, 0.f, 0.f, 0.f);
    if (r0 + r < N) {
      v = *(const float4*)(x + (size_t)(r0 + r) * 64 + c4);
      if (RELU_IN) {
        v.x = fmaxf(v.x, 0.f); v.y = fmaxf(v.y, 0.f);
        v.z = fmaxf(v.z, 0.f); v.w = fmaxf(v.w, 0.f);
      }
    }
    *(float4*)(&xs[r][c4]) = v;
  }
  __syncthreads();
  const int r = t >> 2, j = (t & 3) << 2;
  float4 acc = make_float4(0.f, 0.f, 0.f, 0.f);
  for (int k = 0; k < 64; k++) {
    float a = xs[r][k];
    float4 w = *(const float4*)(&wt[k][j]);
    acc.x = fmaf(a, w.x, acc.x);
    acc.y = fmaf(a, w.y, acc.y);
    acc.z = fmaf(a, w.z, acc.z);
    acc.w = fmaf(a, w.w, acc.w);
  }
  int row = r0 + r;
  if (row < N) *(float4*)(h + (size_t)row * 16 + j) = acc;
}

// Degree histograms, 8-way replicated (replica = blockIdx & 7) to cut
// per-line atomic contention ~8x.
__global__ void hist_k(const int* __restrict__ ei, int* __restrict__ deg_rep,
                       int* __restrict__ indeg_rep, int E, int N) {
  int e = blockIdx.x * blockDim.x + threadIdx.x;
  if (e >= E + N) return;
  int s, d;
  if (e < E) { s = ei[e]; d = ei[E + e]; }
  else       { s = e - E; d = s; }
  int r = blockIdx.x & (REP - 1);
  atomicAdd(deg_rep + r * N + s, 1);
  atomicAdd(indeg_rep + r * N + d, 1);
}

// deg/in_deg = sum over replicas (coalesced reads).
__global__ void reduce_deg_k(const int* __restrict__ deg_rep,
                             const int* __restrict__ indeg_rep,
                             int* __restrict__ deg, int* __restrict__ in_deg, int N) {
  int i = blockIdx.x * blockDim.x + threadIdx.x;
  if (i >= N) return;
  int a = 0, b = 0;
#pragma unroll
  for (int r = 0; r < REP; r++) {
    a += deg_rep[r * N + i];
    b += indeg_rep[r * N + i];
  }
  deg[i] = a;
  in_deg[i] = b;
}

// ---- 3-kernel exclusive scan over in_deg[N] (nbN <= 512) ----
__global__ void scan_reduce_k(const int* __restrict__ v, int* __restrict__ part, int n) {
  __shared__ int l[256];
  int i = blockIdx.x * 256 + threadIdx.x;
  l[threadIdx.x] = (i < n) ? v[i] : 0;
  __syncthreads();
  for (int o = 128; o > 0; o >>= 1) {
    if (threadIdx.x < o) l[threadIdx.x] += l[threadIdx.x + o];
    __syncthreads();
  }
  if (threadIdx.x == 0) part[blockIdx.x] = l[0];
}

__global__ void scan_part_k(int* __restrict__ part, int nb) {  // 1 block, 512 thr
  __shared__ int l[512];
  int t = threadIdx.x;
  int v = (t < nb) ? part[t] : 0;
  l[t] = v;
  __syncthreads();
  for (int o = 1; o < 512; o <<= 1) {
    int a = (t >= o) ? l[t - o] : 0;
    __syncthreads();
    l[t] += a;
    __syncthreads();
  }
  if (t < nb) part[t] = l[t] - v;  // exclusive
}

__global__ void scan_final_k(const int* __restrict__ v, const int* __restrict__ part,
                             int* __restrict__ off, int n) {
  __shared__ int l[256];
  int t = threadIdx.x;
  int i = blockIdx.x * 256 + t;
  int x = (i < n) ? v[i] : 0;
  l[t] = x;
  __syncthreads();
  for (int o = 1; o < 256; o <<= 1) {
    int a = (t >= o) ? l[t - o] : 0;
    __syncthreads();
    l[t] += a;
    __syncthreads();
  }
  if (i < n) off[i] = l[t] - x + part[blockIdx.x];
}

// Convert indeg_rep in place into running slot pointers:
// subptr[r][d] = off[d] + sum_{r'<r} indeg_rep[r'][d].
__global__ void suboff_k(int* __restrict__ indeg_rep, const int* __restrict__ off, int N) {
  int i = blockIdx.x * blockDim.x + threadIdx.x;
  if (i >= N) return;
  int base = off[i];
#pragma unroll
  for (int r = 0; r < REP; r++) {
    int t = indeg_rep[r * N + i];
    indeg_rep[r * N + i] = base;
    base += t;
  }
}

// Per edge: fetch-and-inc replica slot pointer, store src.
// Same edge->replica mapping as hist_k (same grid) => counts match.
__global__ void fill_struct_k(const int* __restrict__ ei, int* __restrict__ subptr,
                              int* __restrict__ csr_src, int E, int N) {
  int e = blockIdx.x * blockDim.x + threadIdx.x;
  if (e >= E + N) return;
  int s, d;
  if (e < E) { s = ei[e]; d = ei[E + e]; }
  else       { s = e - E; d = s; }
  int r = blockIdx.x & (REP - 1);
  int slot = atomicAdd(subptr + r * N + d, 1);
  csr_src[slot] = s;
}

// Alpha pass over CSR: G=D/4 lanes per dst node; lane c holds h[dst] chunk c.
// pos histogram replicated (r = blockIdx & 7).
template <int D>
__global__ void alpha_csr_k(const int* __restrict__ csr_src, const int* __restrict__ off,
                            const int* __restrict__ indeg, const float* __restrict__ h,
                            unsigned char* __restrict__ flagb, int* __restrict__ pos_rep,
                            int N) {
  const int G = D / 4;
  int t = blockIdx.x * 256 + threadIdx.x;
  int node = t / G;
  int c = t & (G - 1);
  if (node >= N) return;
  int* pos = pos_rep + (blockIdx.x & (REP - 1)) * N;
  const float4 hd = *(const float4*)(h + (size_t)node * D + c * 4);
  int j = off[node];
  int je = j + indeg[node];
  for (; j < je; ++j) {
    int s = csr_src[j];  // same addr across G lanes -> broadcast
    float4 hs = *(const float4*)(h + (size_t)s * D + c * 4);
    float p = fmaf(hs.x, hd.x, fmaf(hs.y, hd.y, fmaf(hs.z, hd.z, hs.w * hd.w)));
#pragma unroll
    for (int o = G / 2; o > 0; o >>= 1) p += __shfl_xor(p, o);
    if (c == 0) {
      bool pz = p > 0.f;
      flagb[j] = (unsigned char)pz;
      if (pz) atomicAdd(pos + s, 1);
    }
  }
}

__global__ void denom_k(const int* __restrict__ pos_rep, const int* __restrict__ deg,
                        float* __restrict__ dinv, int N) {
  int i = blockIdx.x * blockDim.x + threadIdx.x;
  if (i >= N) return;
  int p = 0;
#pragma unroll
  for (int r = 0; r < REP; r++) p += pos_rep[r * N + i];
  int dg = deg[i];
  dinv[i] = (p > 0) ? 1.f / ((float)p + (float)(dg - p) * EXPC)
                    : 1.f / (EXPC * (float)dg);
}

// Gather over CSR: G=D/4 lanes per node; acc starts at bias; one write per row.
// FUSE_LSM (D=16): 4-lane log-softmax in-register, writes final output.
template <int D, bool FUSE_LSM>
__global__ void gather_csr_k(const int* __restrict__ csr_src, const int* __restrict__ off,
                             const int* __restrict__ indeg,
                             const unsigned char* __restrict__ flagb,
                             const float* __restrict__ dinv, const float* __restrict__ h,
                             const float* __restrict__ b, float* __restrict__ outp, int N) {
  const int G = D / 4;
  int t = blockIdx.x * 256 + threadIdx.x;
  int node = t / G;
  int c = t & (G - 1);
  if (node >= N) return;
  float4 acc = *(const float4*)(b + c * 4);
  int j = off[node];
  int je = j + indeg[node];
  for (; j < je; ++j) {
    int s = csr_src[j];
    float w = (flagb[j] ? 1.f : EXPC) * dinv[s];
    float4 hv = *(const float4*)(h + (size_t)s * D + c * 4);
    acc.x = fmaf(w, hv.x, acc.x);
    acc.y = fmaf(w, hv.y, acc.y);
    acc.z = fmaf(w, hv.z, acc.z);
    acc.w = fmaf(w, hv.w, acc.w);
  }
  if (FUSE_LSM) {
    float m = fmaxf(fmaxf(acc.x, acc.y), fmaxf(acc.z, acc.w));
    m = fmaxf(m, __shfl_xor(m, 1));
    m = fmaxf(m, __shfl_xor(m, 2));
    float s = expf(acc.x - m) + expf(acc.y - m) + expf(acc.z - m) + expf(acc.w - m);
    s += __shfl_xor(s, 1);
    s += __shfl_xor(s, 2);
    float lse = m + logf(s);
    acc.x -= lse; acc.y -= lse; acc.z -= lse; acc.w -= lse;
  }
  *(float4*)(outp + (size_t)node * D + c * 4) = acc;
}

extern "C" void kernel_launch(void* const* d_in, const int* in_sizes, int n_in,
                              void* d_out, int out_size, void* d_ws, size_t ws_size,
                              hipStream_t stream) {
  const float* x = (const float*)d_in[0];
  const int* ei = (const int*)d_in[1];
  const float* W1 = (const float*)d_in[2];
  const float* b1 = (const float*)d_in[3];
  const float* W2 = (const float*)d_in[4];
  const float* b2 = (const float*)d_in[5];
  float* out = (float*)d_out;

  const int N = in_sizes[0] / 64;
  const int E = in_sizes[1] / 2;
  const int Et = E + N;
  const int B = 256;
  const int nbN = (N + B - 1) / B;  // 391 for N=100k; scan assumes <=512
  const int nbE = (Et + B - 1) / B;
  const int nbT = (N + 63) / 64;    // 64-row GEMM tiles

  // Workspace (~72 MB).
  char* ws = (char*)d_ws;
  float* h1 = (float*)ws;      ws += (size_t)N * 64 * 4;      // 25.6 MB
  float* agg1 = (float*)ws;    ws += (size_t)N * 64 * 4;      // 25.6 MB
  // replicated histograms, contiguous: [deg_rep | indeg_rep | pos_rep]
  int* deg_rep = (int*)ws;     ws += (size_t)REP * N * 4;     // 3.2 MB
  int* indeg_rep = (int*)ws;   ws += (size_t)REP * N * 4;     // 3.2 MB
  int* pos_rep = (int*)ws;     ws += (size_t)REP * N * 4;     // 3.2 MB
  int* deg = (int*)ws;         ws += (size_t)N * 4;
  int* in_deg = (int*)ws;      ws += (size_t)N * 4;
  int* off = (int*)ws;         ws += (size_t)N * 4;
  float* dinv = (float*)ws;    ws += (size_t)N * 4;
  int* part = (int*)ws;        ws += 512 * 4;
  int* csr_src = (int*)ws;     ws += (size_t)Et * 4;          // 6.8 MB
  unsigned char* flagb = (unsigned char*)ws; ws += (size_t)Et;
  float* h2 = h1;  // alias: h1 dead once gather1 completes

  // ---- CSR structure (data-independent, built once) ----
  hipLaunchKernelGGL(zero_i32, dim3((3 * REP * N + B - 1) / B), dim3(B), 0, stream,
                     deg_rep, 3 * REP * N);
  hipLaunchKernelGGL(hist_k, dim3(nbE), dim3(B), 0, stream, ei, deg_rep, indeg_rep, E, N);
  hipLaunchKernelGGL(reduce_deg_k, dim3(nbN), dim3(B), 0, stream,
                     deg_rep, indeg_rep, deg, in_deg, N);
  hipLaunchKernelGGL(scan_reduce_k, dim3(nbN), dim3(B), 0, stream, in_deg, part, N);
  hipLaunchKernelGGL(scan_part_k, dim3(1), dim3(512), 0, stream, part, nbN);
  hipLaunchKernelGGL(scan_final_k, dim3(nbN), dim3(B), 0, stream, in_deg, part, off, N);
  hipLaunchKernelGGL(suboff_k, dim3(nbN), dim3(B), 0, stream, indeg_rep, off, N);
  hipLaunchKernelGGL(fill_struct_k, dim3(nbE), dim3(B), 0, stream, ei, indeg_rep, csr_src, E, N);

  // ---- layer 1 (D=64) ----
  hipLaunchKernelGGL((gemm64_k<false>), dim3(nbT), dim3(B), 0, stream, x, W1, h1, N);
  hipLaunchKernelGGL((alpha_csr_k<64>), dim3(((size_t)N * 16 + B - 1) / B), dim3(B), 0,
                     stream, csr_src, off, in_deg, h1, flagb, pos_rep, N);
  hipLaunchKernelGGL(denom_k, dim3(nbN), dim3(B), 0, stream, pos_rep, deg, dinv, N);
  hipLaunchKernelGGL((gather_csr_k<64, false>), dim3(((size_t)N * 16 + B - 1) / B), dim3(B),
                     0, stream, csr_src, off, in_deg, flagb, dinv, h1, b1, agg1, N);

  // ---- layer 2 (D=16): relu folded into gemm load, log-softmax fused ----
  hipLaunchKernelGGL(zero_i32, dim3((REP * N + B - 1) / B), dim3(B), 0, stream,
                     pos_rep, REP * N);
  hipLaunchKernelGGL((gemm16_k<true>), dim3(nbT), dim3(B), 0, stream, agg1, W2, h2, N);
  hipLaunchKernelGGL((alpha_csr_k<16>), dim3(((size_t)N * 4 + B - 1) / B), dim3(B), 0,
                     stream, csr_src, off, in_deg, h2, flagb, pos_rep, N);
  hipLaunchKernelGGL(denom_k, dim3(nbN), dim3(B), 0, stream, pos_rep, deg, dinv, N);
  hipLaunchKernelGGL((gather_csr_k<16, true>), dim3(((size_t)N * 4 + B - 1) / B), dim3(B),
                     0, stream, csr_src, off, in_deg, flagb, dinv, h2, b2, out, N);
}

// Round 10
// 523.089 us; speedup vs baseline: 1.2898x; 1.2898x over previous
//
#include <hip/hip_runtime.h>

// GAT (2-layer) on MI355X — partition-built CSR + LDS-tiled GEMMs.
// Closed-form segment softmax: alpha in {+t,-t}; per-src s: p=#pos out-edges,
// deg=out-degree (incl self-loop).
//   w = (flag?1:c) * dinv[s],  dinv = p>0 ? 1/(p+(deg-p)c) : 1/(c*deg).
// edge_index arrives as int32 (harness converts integer inputs).
// R5: per-thread W arrays spill -> W in LDS.   R6: need __launch_bounds__,
// pad LDS tiles.   R7/R8: (256,1) frees VGPRs -> no spill.
// R8: naive hist = cross-XCD atomic line ping-pong.
// R9: fill's scattered 4B stores -> 64B/line write amplification (104MB for
//     6.8MB payload). Fix: two-level partition (coarse bucket = node>>8);
//     per-bucket segments are block-local -> L2 write-combines the scatter.
#define EXPC 0.13533528323661270f  // exp(-2*1.0)
#define REP 8
#define CHUNK 16384  // edges per partition block

__global__ void zero_i32(int* __restrict__ p, int n) {
  int i = blockIdx.x * blockDim.x + threadIdx.x;
  if (i < n) p[i] = 0;
}

// ---------------- GEMMs (unchanged from R8) ----------------
template <bool RELU_IN>
__global__ void __launch_bounds__(256, 1)
gemm64_k(const float* __restrict__ x, const float* __restrict__ W,
         float* __restrict__ h, int N) {
  __shared__ float xs[64][68];
  __shared__ float wt[64][68];  // wt[k][c] = W[c][k]
  const int t = threadIdx.x;
  const int r0 = blockIdx.x * 64;
  for (int i = t; i < 4096; i += 256) {
    int c = i >> 6, k = i & 63;
    wt[k][c] = W[i];
  }
  for (int s = t; s < 1024; s += 256) {
    int r = s >> 4, c4 = (s & 15) << 2;
    float4 v = make_float4(0.f, 0.f, 0.f, 0.f);
    if (r0 + r < N) {
      v = *(const float4*)(x + (size_t)(r0 + r) * 64 + c4);
      if (RELU_IN) {
        v.x = fmaxf(v.x, 0.f); v.y = fmaxf(v.y, 0.f);
        v.z = fmaxf(v.z, 0.f); v.w = fmaxf(v.w, 0.f);
      }
    }
    *(float4*)(&xs[r][c4]) = v;
  }
  __syncthreads();
  const int ty = t >> 4, tx = t & 15;
  float acc[4][4] = {};
  for (int kk = 0; kk < 64; kk += 4) {
    float4 a[4], w[4];
#pragma unroll
    for (int i = 0; i < 4; i++) a[i] = *(const float4*)(&xs[4 * ty + i][kk]);
#pragma unroll
    for (int m = 0; m < 4; m++) w[m] = *(const float4*)(&wt[kk + m][4 * tx]);
#pragma unroll
    for (int i = 0; i < 4; i++) {
      acc[i][0] = fmaf(a[i].x, w[0].x, fmaf(a[i].y, w[1].x,
                  fmaf(a[i].z, w[2].x, fmaf(a[i].w, w[3].x, acc[i][0]))));
      acc[i][1] = fmaf(a[i].x, w[0].y, fmaf(a[i].y, w[1].y,
                  fmaf(a[i].z, w[2].y, fmaf(a[i].w, w[3].y, acc[i][1]))));
      acc[i][2] = fmaf(a[i].x, w[0].z, fmaf(a[i].y, w[1].z,
                  fmaf(a[i].z, w[2].z, fmaf(a[i].w, w[3].z, acc[i][2]))));
      acc[i][3] = fmaf(a[i].x, w[0].w, fmaf(a[i].y, w[1].w,
                  fmaf(a[i].z, w[2].w, fmaf(a[i].w, w[3].w, acc[i][3]))));
    }
  }
#pragma unroll
  for (int i = 0; i < 4; i++) {
    int row = r0 + 4 * ty + i;
    if (row < N)
      *(float4*)(h + (size_t)row * 64 + 4 * tx) =
          make_float4(acc[i][0], acc[i][1], acc[i][2], acc[i][3]);
  }
}

template <bool RELU_IN>
__global__ void __launch_bounds__(256, 2)
gemm16_k(const float* __restrict__ x, const float* __restrict__ W,
         float* __restrict__ h, int N) {
  __shared__ float xs[64][68];
  __shared__ float wt[64][20];
  const int t = threadIdx.x;
  const int r0 = blockIdx.x * 64;
  for (int i = t; i < 1024; i += 256) {
    int c = i >> 6, k = i & 63;
    wt[k][c] = W[i];
  }
  for (int s = t; s < 1024; s += 256) {
    int r = s >> 4, c4 = (s & 15) << 2;
    float4 v = make_float4(0.f, 0.f, 0.f, 0.f);
    if (r0 + r < N) {
      v = *(const float4*)(x + (size_t)(r0 + r) * 64 + c4);
      if (RELU_IN) {
        v.x = fmaxf(v.x, 0.f); v.y = fmaxf(v.y, 0.f);
        v.z = fmaxf(v.z, 0.f); v.w = fmaxf(v.w, 0.f);
      }
    }
    *(float4*)(&xs[r][c4]) = v;
  }
  __syncthreads();
  const int r = t >> 2, j = (t & 3) << 2;
  float4 acc = make_float4(0.f, 0.f, 0.f, 0.f);
  for (int k = 0; k < 64; k++) {
    float a = xs[r][k];
    float4 w = *(const float4*)(&wt[k][j]);
    acc.x = fmaf(a, w.x, acc.x);
    acc.y = fmaf(a, w.y, acc.y);
    acc.z = fmaf(a, w.z, acc.z);
    acc.w = fmaf(a, w.w, acc.w);
  }
  int row = r0 + r;
  if (row < N) *(float4*)(h + (size_t)row * 16 + j) = acc;
}

// ---------------- partition-based CSR build ----------------
// Pass A: coarse histograms (bucket = node>>8) for dst and src, LDS-aggregated.
__global__ void passA_k(const int* __restrict__ ei, int* __restrict__ chd,
                        int* __restrict__ chs, int E, int Et) {
  __shared__ int ld[512], ls[512];
  int t = threadIdx.x;
  for (int i = t; i < 512; i += 256) { ld[i] = 0; ls[i] = 0; }
  __syncthreads();
  int base = blockIdx.x * CHUNK;
  int end = base + CHUNK; if (end > Et) end = Et;
  for (int e = base + t; e < end; e += 256) {
    int s, d;
    if (e < E) { s = ei[e]; d = ei[E + e]; } else { s = e - E; d = s; }
    atomicAdd(&ld[d >> 8], 1);
    atomicAdd(&ls[s >> 8], 1);
  }
  __syncthreads();
  for (int i = t; i < 512; i += 256) {
    if (ld[i]) atomicAdd(chd + i, ld[i]);
    if (ls[i]) atomicAdd(chs + i, ls[i]);
  }
}

// Exclusive scan of both coarse hists (NB <= 512); writes base + cursor copies.
__global__ void scan2_k(const int* __restrict__ chd, const int* __restrict__ chs,
                        int* __restrict__ cbd, int* __restrict__ cbs,
                        int* __restrict__ cud, int* __restrict__ cus, int NB) {
  __shared__ int l[512];
  int t = threadIdx.x;
  for (int pass = 0; pass < 2; ++pass) {
    const int* src = pass ? chs : chd;
    int* db = pass ? cbs : cbd;
    int* dc = pass ? cus : cud;
    int v = (t < NB) ? src[t] : 0;
    l[t] = v;
    __syncthreads();
    for (int o = 1; o < 512; o <<= 1) {
      int a = (t >= o) ? l[t - o] : 0;
      __syncthreads();
      l[t] += a;
      __syncthreads();
    }
    if (t < NB) { int e = l[t] - v; db[t] = e; dc[t] = e; }
    __syncthreads();
  }
}

// Pass B: scatter edges into coarse partitions.
// dst record: src | (dstLow8 << 17)  (src < 2^17). src record: srcLow8 byte.
__global__ void passB_k(const int* __restrict__ ei, int* __restrict__ cud,
                        int* __restrict__ cus, int* __restrict__ part_dst,
                        unsigned char* __restrict__ part_src, int E, int Et) {
  __shared__ int cntd[512], cnts[512], based[512], bases[512];
  int t = threadIdx.x;
  for (int i = t; i < 512; i += 256) { cntd[i] = 0; cnts[i] = 0; }
  __syncthreads();
  int base = blockIdx.x * CHUNK;
  int end = base + CHUNK; if (end > Et) end = Et;
  for (int e = base + t; e < end; e += 256) {  // phase 1: local counts
    int s, d;
    if (e < E) { s = ei[e]; d = ei[E + e]; } else { s = e - E; d = s; }
    atomicAdd(&cntd[d >> 8], 1);
    atomicAdd(&cnts[s >> 8], 1);
  }
  __syncthreads();
  for (int i = t; i < 512; i += 256) {  // phase 2: claim ranges
    based[i] = cntd[i] ? atomicAdd(cud + i, cntd[i]) : 0;
    bases[i] = cnts[i] ? atomicAdd(cus + i, cnts[i]) : 0;
    cntd[i] = 0; cnts[i] = 0;
  }
  __syncthreads();
  for (int e = base + t; e < end; e += 256) {  // phase 3: scatter
    int s, d;
    if (e < E) { s = ei[e]; d = ei[E + e]; } else { s = e - E; d = s; }
    int bd = d >> 8, bs = s >> 8;
    int rd = atomicAdd(&cntd[bd], 1);
    int rs = atomicAdd(&cnts[bs], 1);
    part_dst[based[bd] + rd] = s | ((d & 255) << 17);
    part_src[bases[bs] + rs] = (unsigned char)(s & 255);
  }
}

// Pass C (dst): per-bucket fine CSR. Block b owns nodes [b*256, b*256+256).
// Scatter stays inside the bucket's ~17KB csr segment -> L2 write-combines.
__global__ void passC_k(const int* __restrict__ part_dst, const int* __restrict__ cbd,
                        const int* __restrict__ chd, int* __restrict__ csr_src,
                        int* __restrict__ in_deg, int* __restrict__ off, int N) {
  __shared__ int hist[256], loff[256], rank[256];
  int b = blockIdx.x, t = threadIdx.x;
  int segbase = cbd[b], segcnt = chd[b];
  hist[t] = 0; rank[t] = 0;
  __syncthreads();
  for (int i = t; i < segcnt; i += 256)
    atomicAdd(&hist[part_dst[segbase + i] >> 17], 1);
  __syncthreads();
  int x = hist[t];
  loff[t] = x;
  __syncthreads();
  for (int o = 1; o < 256; o <<= 1) {
    int a = (t >= o) ? loff[t - o] : 0;
    __syncthreads();
    loff[t] += a;
    __syncthreads();
  }
  int excl = loff[t] - x;
  int node = (b << 8) + t;
  if (node < N) { in_deg[node] = x; off[node] = segbase + excl; }
  __syncthreads();
  loff[t] = excl;
  __syncthreads();
  for (int i = t; i < segcnt; i += 256) {
    int rec = part_dst[segbase + i];
    int dl = rec >> 17;
    int r = atomicAdd(&rank[dl], 1);
    csr_src[segbase + loff[dl] + r] = rec & 0x1FFFF;
  }
}

// Pass C' (src): fine counts only -> deg.
__global__ void passCs_k(const unsigned char* __restrict__ part_src,
                         const int* __restrict__ cbs, const int* __restrict__ chs,
                         int* __restrict__ deg, int N) {
  __shared__ int hist[256];
  int b = blockIdx.x, t = threadIdx.x;
  int segbase = cbs[b], segcnt = chs[b];
  hist[t] = 0;
  __syncthreads();
  for (int i = t; i < segcnt; i += 256)
    atomicAdd(&hist[part_src[segbase + i]], 1);
  __syncthreads();
  int node = (b << 8) + t;
  if (node < N) deg[node] = hist[t];
}

// ---------------- per-layer passes (unchanged from R9) ----------------
template <int D>
__global__ void alpha_csr_k(const int* __restrict__ csr_src, const int* __restrict__ off,
                            const int* __restrict__ indeg, const float* __restrict__ h,
                            unsigned char* __restrict__ flagb, int* __restrict__ pos_rep,
                            int N) {
  const int G = D / 4;
  int t = blockIdx.x * 256 + threadIdx.x;
  int node = t / G;
  int c = t & (G - 1);
  if (node >= N) return;
  int* pos = pos_rep + (blockIdx.x & (REP - 1)) * N;
  const float4 hd = *(const float4*)(h + (size_t)node * D + c * 4);
  int j = off[node];
  int je = j + indeg[node];
  for (; j < je; ++j) {
    int s = csr_src[j];
    float4 hs = *(const float4*)(h + (size_t)s * D + c * 4);
    float p = fmaf(hs.x, hd.x, fmaf(hs.y, hd.y, fmaf(hs.z, hd.z, hs.w * hd.w)));
#pragma unroll
    for (int o = G / 2; o > 0; o >>= 1) p += __shfl_xor(p, o);
    if (c == 0) {
      bool pz = p > 0.f;
      flagb[j] = (unsigned char)pz;
      if (pz) atomicAdd(pos + s, 1);
    }
  }
}

__global__ void denom_k(const int* __restrict__ pos_rep, const int* __restrict__ deg,
                        float* __restrict__ dinv, int N) {
  int i = blockIdx.x * blockDim.x + threadIdx.x;
  if (i >= N) return;
  int p = 0;
#pragma unroll
  for (int r = 0; r < REP; r++) p += pos_rep[r * N + i];
  int dg = deg[i];
  dinv[i] = (p > 0) ? 1.f / ((float)p + (float)(dg - p) * EXPC)
                    : 1.f / (EXPC * (float)dg);
}

template <int D, bool FUSE_LSM>
__global__ void gather_csr_k(const int* __restrict__ csr_src, const int* __restrict__ off,
                             const int* __restrict__ indeg,
                             const unsigned char* __restrict__ flagb,
                             const float* __restrict__ dinv, const float* __restrict__ h,
                             const float* __restrict__ b, float* __restrict__ outp, int N) {
  const int G = D / 4;
  int t = blockIdx.x * 256 + threadIdx.x;
  int node = t / G;
  int c = t & (G - 1);
  if (node >= N) return;
  float4 acc = *(const float4*)(b + c * 4);
  int j = off[node];
  int je = j + indeg[node];
  for (; j < je; ++j) {
    int s = csr_src[j];
    float w = (flagb[j] ? 1.f : EXPC) * dinv[s];
    float4 hv = *(const float4*)(h + (size_t)s * D + c * 4);
    acc.x = fmaf(w, hv.x, acc.x);
    acc.y = fmaf(w, hv.y, acc.y);
    acc.z = fmaf(w, hv.z, acc.z);
    acc.w = fmaf(w, hv.w, acc.w);
  }
  if (FUSE_LSM) {
    float m = fmaxf(fmaxf(acc.x, acc.y), fmaxf(acc.z, acc.w));
    m = fmaxf(m, __shfl_xor(m, 1));
    m = fmaxf(m, __shfl_xor(m, 2));
    float s = expf(acc.x - m) + expf(acc.y - m) + expf(acc.z - m) + expf(acc.w - m);
    s += __shfl_xor(s, 1);
    s += __shfl_xor(s, 2);
    float lse = m + logf(s);
    acc.x -= lse; acc.y -= lse; acc.z -= lse; acc.w -= lse;
  }
  *(float4*)(outp + (size_t)node * D + c * 4) = acc;
}

extern "C" void kernel_launch(void* const* d_in, const int* in_sizes, int n_in,
                              void* d_out, int out_size, void* d_ws, size_t ws_size,
                              hipStream_t stream) {
  const float* x = (const float*)d_in[0];
  const int* ei = (const int*)d_in[1];
  const float* W1 = (const float*)d_in[2];
  const float* b1 = (const float*)d_in[3];
  const float* W2 = (const float*)d_in[4];
  const float* b2 = (const float*)d_in[5];
  float* out = (float*)d_out;

  const int N = in_sizes[0] / 64;
  const int E = in_sizes[1] / 2;
  const int Et = E + N;
  const int B = 256;
  const int nbN = (N + B - 1) / B;
  const int nbT = (N + 63) / 64;         // GEMM tiles
  const int NB = (N + 255) >> 8;         // coarse buckets (391), <= 512
  const int nbP = (Et + CHUNK - 1) / CHUNK;  // partition chunks

  // Workspace (~68 MB). part arrays dead after pass C/C' -> pos_rep/flagb alias.
  char* ws = (char*)d_ws;
  float* h1 = (float*)ws;    ws += (size_t)N * 64 * 4;   // 25.6 MB
  float* agg1 = (float*)ws;  ws += (size_t)N * 64 * 4;   // 25.6 MB
  int* deg = (int*)ws;       ws += (size_t)N * 4;
  int* in_deg = (int*)ws;    ws += (size_t)N * 4;
  int* off = (int*)ws;       ws += (size_t)N * 4;
  float* dinv = (float*)ws;  ws += (size_t)N * 4;
  int* chd = (int*)ws;       ws += 512 * 4;  // coarse hist dst
  int* chs = (int*)ws;       ws += 512 * 4;  // coarse hist src
  int* cbd = (int*)ws;       ws += 512 * 4;  // coarse base dst (persist)
  int* cbs = (int*)ws;       ws += 512 * 4;
  int* cud = (int*)ws;       ws += 512 * 4;  // cursors (mutated in pass B)
  int* cus = (int*)ws;       ws += 512 * 4;
  int* csr_src = (int*)ws;   ws += (size_t)Et * 4;       // 6.8 MB
  char* P = ws;              ws += (size_t)Et * 4 + (size_t)Et;  // 8.5 MB
  int* part_dst = (int*)P;
  unsigned char* part_src = (unsigned char*)(P + (size_t)Et * 4);
  int* pos_rep = (int*)P;                       // alias (after pass C/C')
  unsigned char* flagb = (unsigned char*)(P + (size_t)REP * N * 4);

  // ---- CSR structure (partition pipeline, data-independent) ----
  hipLaunchKernelGGL(zero_i32, dim3(4), dim3(B), 0, stream, chd, 1024);  // chd+chs
  hipLaunchKernelGGL(passA_k, dim3(nbP), dim3(B), 0, stream, ei, chd, chs, E, Et);
  hipLaunchKernelGGL(scan2_k, dim3(1), dim3(512), 0, stream, chd, chs, cbd, cbs, cud, cus, NB);
  hipLaunchKernelGGL(passB_k, dim3(nbP), dim3(B), 0, stream, ei, cud, cus,
                     part_dst, part_src, E, Et);
  hipLaunchKernelGGL(passC_k, dim3(NB), dim3(B), 0, stream, part_dst, cbd, chd,
                     csr_src, in_deg, off, N);
  hipLaunchKernelGGL(passCs_k, dim3(NB), dim3(B), 0, stream, part_src, cbs, chs, deg, N);

  // ---- layer 1 (D=64) ----
  hipLaunchKernelGGL((gemm64_k<false>), dim3(nbT), dim3(B), 0, stream, x, W1, h1, N);
  hipLaunchKernelGGL(zero_i32, dim3((REP * N + B - 1) / B), dim3(B), 0, stream,
                     pos_rep, REP * N);
  hipLaunchKernelGGL((alpha_csr_k<64>), dim3(((size_t)N * 16 + B - 1) / B), dim3(B), 0,
                     stream, csr_src, off, in_deg, h1, flagb, pos_rep, N);
  hipLaunchKernelGGL(denom_k, dim3(nbN), dim3(B), 0, stream, pos_rep, deg, dinv, N);
  hipLaunchKernelGGL((gather_csr_k<64, false>), dim3(((size_t)N * 16 + B - 1) / B), dim3(B),
                     0, stream, csr_src, off, in_deg, flagb, dinv, h1, b1, agg1, N);

  // ---- layer 2 (D=16): relu folded into gemm load, log-softmax fused ----
  float* h2 = h1;  // alias: h1 dead once gather1 completes
  hipLaunchKernelGGL((gemm16_k<true>), dim3(nbT), dim3(B), 0, stream, agg1, W2, h2, N);
  hipLaunchKernelGGL(zero_i32, dim3((REP * N + B - 1) / B), dim3(B), 0, stream,
                     pos_rep, REP * N);
  hipLaunchKernelGGL((alpha_csr_k<16>), dim3(((size_t)N * 4 + B - 1) / B), dim3(B), 0,
                     stream, csr_src, off, in_deg, h2, flagb, pos_rep, N);
  hipLaunchKernelGGL(denom_k, dim3(nbN), dim3(B), 0, stream, pos_rep, deg, dinv, N);
  hipLaunchKernelGGL((gather_csr_k<16, true>), dim3(((size_t)N * 4 + B - 1) / B), dim3(B),
                     0, stream, csr_src, off, in_deg, flagb, dinv, h2, b2, out, N);
}

// Round 11
// 486.539 us; speedup vs baseline: 1.3867x; 1.0751x over previous
//
#include <hip/hip_runtime.h>

// GAT (2-layer) on MI355X — partition-built CSR + LDS-tiled GEMMs +
// MLP-unrolled edge passes, h pre-scaled by dinv.
// Closed-form segment softmax: alpha in {+t,-t}; per-src s: p=#pos out-edges,
// deg=out-degree (incl self-loop).
//   w = (flag?1:c) * dinv[s],  dinv = p>0 ? 1/(p+(deg-p)c) : 1/(c*deg).
// After alpha: h[s] *= dinv[s] (in place) -> gather weight is (flag?1:c).
// edge_index arrives as int32 (harness converts integer inputs).
// R5: W reg-arrays spill -> W in LDS.  R6/R7/R8: __launch_bounds__(256,1)
// frees VGPRs; pad LDS tiles.  R8: naive hist = cross-XCD line ping-pong.
// R9: scattered 4B stores = 64B/line write amp -> partition build (R10).
// R10: alpha/gather latency-bound (VALUBusy 18%, 1 row-load in flight/group)
//      -> 4-edge unroll + kill dinv random load.
#define EXPC 0.13533528323661270f  // exp(-2*1.0)
#define REP 8
#define CHUNK 16384  // edges per partition block

__global__ void zero_i32(int* __restrict__ p, int n) {
  int i = blockIdx.x * blockDim.x + threadIdx.x;
  if (i < n) p[i] = 0;
}

// ---------------- GEMMs (unchanged from R8) ----------------
template <bool RELU_IN>
__global__ void __launch_bounds__(256, 1)
gemm64_k(const float* __restrict__ x, const float* __restrict__ W,
         float* __restrict__ h, int N) {
  __shared__ float xs[64][68];
  __shared__ float wt[64][68];  // wt[k][c] = W[c][k]
  const int t = threadIdx.x;
  const int r0 = blockIdx.x * 64;
  for (int i = t; i < 4096; i += 256) {
    int c = i >> 6, k = i & 63;
    wt[k][c] = W[i];
  }
  for (int s = t; s < 1024; s += 256) {
    int r = s >> 4, c4 = (s & 15) << 2;
    float4 v = make_float4(0.f, 0.f, 0.f, 0.f);
    if (r0 + r < N) {
      v = *(const float4*)(x + (size_t)(r0 + r) * 64 + c4);
      if (RELU_IN) {
        v.x = fmaxf(v.x, 0.f); v.y = fmaxf(v.y, 0.f);
        v.z = fmaxf(v.z, 0.f); v.w = fmaxf(v.w, 0.f);
      }
    }
    *(float4*)(&xs[r][c4]) = v;
  }
  __syncthreads();
  const int ty = t >> 4, tx = t & 15;
  float acc[4][4] = {};
  for (int kk = 0; kk < 64; kk += 4) {
    float4 a[4], w[4];
#pragma unroll
    for (int i = 0; i < 4; i++) a[i] = *(const float4*)(&xs[4 * ty + i][kk]);
#pragma unroll
    for (int m = 0; m < 4; m++) w[m] = *(const float4*)(&wt[kk + m][4 * tx]);
#pragma unroll
    for (int i = 0; i < 4; i++) {
      acc[i][0] = fmaf(a[i].x, w[0].x, fmaf(a[i].y, w[1].x,
                  fmaf(a[i].z, w[2].x, fmaf(a[i].w, w[3].x, acc[i][0]))));
      acc[i][1] = fmaf(a[i].x, w[0].y, fmaf(a[i].y, w[1].y,
                  fmaf(a[i].z, w[2].y, fmaf(a[i].w, w[3].y, acc[i][1]))));
      acc[i][2] = fmaf(a[i].x, w[0].z, fmaf(a[i].y, w[1].z,
                  fmaf(a[i].z, w[2].z, fmaf(a[i].w, w[3].z, acc[i][2]))));
      acc[i][3] = fmaf(a[i].x, w[0].w, fmaf(a[i].y, w[1].w,
                  fmaf(a[i].z, w[2].w, fmaf(a[i].w, w[3].w, acc[i][3]))));
    }
  }
#pragma unroll
  for (int i = 0; i < 4; i++) {
    int row = r0 + 4 * ty + i;
    if (row < N)
      *(float4*)(h + (size_t)row * 64 + 4 * tx) =
          make_float4(acc[i][0], acc[i][1], acc[i][2], acc[i][3]);
  }
}

template <bool RELU_IN>
__global__ void __launch_bounds__(256, 2)
gemm16_k(const float* __restrict__ x, const float* __restrict__ W,
         float* __restrict__ h, int N) {
  __shared__ float xs[64][68];
  __shared__ float wt[64][20];
  const int t = threadIdx.x;
  const int r0 = blockIdx.x * 64;
  for (int i = t; i < 1024; i += 256) {
    int c = i >> 6, k = i & 63;
    wt[k][c] = W[i];
  }
  for (int s = t; s < 1024; s += 256) {
    int r = s >> 4, c4 = (s & 15) << 2;
    float4 v = make_float4(0.f, 0.f, 0.f, 0.f);
    if (r0 + r < N) {
      v = *(const float4*)(x + (size_t)(r0 + r) * 64 + c4);
      if (RELU_IN) {
        v.x = fmaxf(v.x, 0.f); v.y = fmaxf(v.y, 0.f);
        v.z = fmaxf(v.z, 0.f); v.w = fmaxf(v.w, 0.f);
      }
    }
    *(float4*)(&xs[r][c4]) = v;
  }
  __syncthreads();
  const int r = t >> 2, j = (t & 3) << 2;
  float4 acc = make_float4(0.f, 0.f, 0.f, 0.f);
  for (int k = 0; k < 64; k++) {
    float a = xs[r][k];
    float4 w = *(const float4*)(&wt[k][j]);
    acc.x = fmaf(a, w.x, acc.x);
    acc.y = fmaf(a, w.y, acc.y);
    acc.z = fmaf(a, w.z, acc.z);
    acc.w = fmaf(a, w.w, acc.w);
  }
  int row = r0 + r;
  if (row < N) *(float4*)(h + (size_t)row * 16 + j) = acc;
}

// ---------------- partition-based CSR build (unchanged from R10) ----------------
__global__ void passA_k(const int* __restrict__ ei, int* __restrict__ chd,
                        int* __restrict__ chs, int E, int Et) {
  __shared__ int ld[512], ls[512];
  int t = threadIdx.x;
  for (int i = t; i < 512; i += 256) { ld[i] = 0; ls[i] = 0; }
  __syncthreads();
  int base = blockIdx.x * CHUNK;
  int end = base + CHUNK; if (end > Et) end = Et;
  for (int e = base + t; e < end; e += 256) {
    int s, d;
    if (e < E) { s = ei[e]; d = ei[E + e]; } else { s = e - E; d = s; }
    atomicAdd(&ld[d >> 8], 1);
    atomicAdd(&ls[s >> 8], 1);
  }
  __syncthreads();
  for (int i = t; i < 512; i += 256) {
    if (ld[i]) atomicAdd(chd + i, ld[i]);
    if (ls[i]) atomicAdd(chs + i, ls[i]);
  }
}

__global__ void scan2_k(const int* __restrict__ chd, const int* __restrict__ chs,
                        int* __restrict__ cbd, int* __restrict__ cbs,
                        int* __restrict__ cud, int* __restrict__ cus, int NB) {
  __shared__ int l[512];
  int t = threadIdx.x;
  for (int pass = 0; pass < 2; ++pass) {
    const int* src = pass ? chs : chd;
    int* db = pass ? cbs : cbd;
    int* dc = pass ? cus : cud;
    int v = (t < NB) ? src[t] : 0;
    l[t] = v;
    __syncthreads();
    for (int o = 1; o < 512; o <<= 1) {
      int a = (t >= o) ? l[t - o] : 0;
      __syncthreads();
      l[t] += a;
      __syncthreads();
    }
    if (t < NB) { int e = l[t] - v; db[t] = e; dc[t] = e; }
    __syncthreads();
  }
}

__global__ void passB_k(const int* __restrict__ ei, int* __restrict__ cud,
                        int* __restrict__ cus, int* __restrict__ part_dst,
                        unsigned char* __restrict__ part_src, int E, int Et) {
  __shared__ int cntd[512], cnts[512], based[512], bases[512];
  int t = threadIdx.x;
  for (int i = t; i < 512; i += 256) { cntd[i] = 0; cnts[i] = 0; }
  __syncthreads();
  int base = blockIdx.x * CHUNK;
  int end = base + CHUNK; if (end > Et) end = Et;
  for (int e = base + t; e < end; e += 256) {
    int s, d;
    if (e < E) { s = ei[e]; d = ei[E + e]; } else { s = e - E; d = s; }
    atomicAdd(&cntd[d >> 8], 1);
    atomicAdd(&cnts[s >> 8], 1);
  }
  __syncthreads();
  for (int i = t; i < 512; i += 256) {
    based[i] = cntd[i] ? atomicAdd(cud + i, cntd[i]) : 0;
    bases[i] = cnts[i] ? atomicAdd(cus + i, cnts[i]) : 0;
    cntd[i] = 0; cnts[i] = 0;
  }
  __syncthreads();
  for (int e = base + t; e < end; e += 256) {
    int s, d;
    if (e < E) { s = ei[e]; d = ei[E + e]; } else { s = e - E; d = s; }
    int bd = d >> 8, bs = s >> 8;
    int rd = atomicAdd(&cntd[bd], 1);
    int rs = atomicAdd(&cnts[bs], 1);
    part_dst[based[bd] + rd] = s | ((d & 255) << 17);
    part_src[bases[bs] + rs] = (unsigned char)(s & 255);
  }
}

__global__ void passC_k(const int* __restrict__ part_dst, const int* __restrict__ cbd,
                        const int* __restrict__ chd, int* __restrict__ csr_src,
                        int* __restrict__ in_deg, int* __restrict__ off, int N) {
  __shared__ int hist[256], loff[256], rank[256];
  int b = blockIdx.x, t = threadIdx.x;
  int segbase = cbd[b], segcnt = chd[b];
  hist[t] = 0; rank[t] = 0;
  __syncthreads();
  for (int i = t; i < segcnt; i += 256)
    atomicAdd(&hist[part_dst[segbase + i] >> 17], 1);
  __syncthreads();
  int x = hist[t];
  loff[t] = x;
  __syncthreads();
  for (int o = 1; o < 256; o <<= 1) {
    int a = (t >= o) ? loff[t - o] : 0;
    __syncthreads();
    loff[t] += a;
    __syncthreads();
  }
  int excl = loff[t] - x;
  int node = (b << 8) + t;
  if (node < N) { in_deg[node] = x; off[node] = segbase + excl; }
  __syncthreads();
  loff[t] = excl;
  __syncthreads();
  for (int i = t; i < segcnt; i += 256) {
    int rec = part_dst[segbase + i];
    int dl = rec >> 17;
    int r = atomicAdd(&rank[dl], 1);
    csr_src[segbase + loff[dl] + r] = rec & 0x1FFFF;
  }
}

__global__ void passCs_k(const unsigned char* __restrict__ part_src,
                         const int* __restrict__ cbs, const int* __restrict__ chs,
                         int* __restrict__ deg, int N) {
  __shared__ int hist[256];
  int b = blockIdx.x, t = threadIdx.x;
  int segbase = cbs[b], segcnt = chs[b];
  hist[t] = 0;
  __syncthreads();
  for (int i = t; i < segcnt; i += 256)
    atomicAdd(&hist[part_src[segbase + i]], 1);
  __syncthreads();
  int node = (b << 8) + t;
  if (node < N) deg[node] = hist[t];
}

// ---------------- per-layer edge passes (4-edge unrolled) ----------------
template <int D>
__global__ void alpha_csr_k(const int* __restrict__ csr_src, const int* __restrict__ off,
                            const int* __restrict__ indeg, const float* __restrict__ h,
                            unsigned char* __restrict__ flagb, int* __restrict__ pos_rep,
                            int N) {
  const int G = D / 4;
  int t = blockIdx.x * 256 + threadIdx.x;
  int node = t / G;
  int c = t & (G - 1);
  if (node >= N) return;
  int* pos = pos_rep + (blockIdx.x & (REP - 1)) * N;
  const float4 hd = *(const float4*)(h + (size_t)node * D + c * 4);
  int j = off[node];
  int je = j + indeg[node];
  for (; j + 4 <= je; j += 4) {
    int s0 = csr_src[j], s1 = csr_src[j + 1], s2 = csr_src[j + 2], s3 = csr_src[j + 3];
    float4 a0 = *(const float4*)(h + (size_t)s0 * D + c * 4);
    float4 a1 = *(const float4*)(h + (size_t)s1 * D + c * 4);
    float4 a2 = *(const float4*)(h + (size_t)s2 * D + c * 4);
    float4 a3 = *(const float4*)(h + (size_t)s3 * D + c * 4);
    float p0 = fmaf(a0.x, hd.x, fmaf(a0.y, hd.y, fmaf(a0.z, hd.z, a0.w * hd.w)));
    float p1 = fmaf(a1.x, hd.x, fmaf(a1.y, hd.y, fmaf(a1.z, hd.z, a1.w * hd.w)));
    float p2 = fmaf(a2.x, hd.x, fmaf(a2.y, hd.y, fmaf(a2.z, hd.z, a2.w * hd.w)));
    float p3 = fmaf(a3.x, hd.x, fmaf(a3.y, hd.y, fmaf(a3.z, hd.z, a3.w * hd.w)));
#pragma unroll
    for (int o = G / 2; o > 0; o >>= 1) {
      p0 += __shfl_xor(p0, o);
      p1 += __shfl_xor(p1, o);
      p2 += __shfl_xor(p2, o);
      p3 += __shfl_xor(p3, o);
    }
    if (c == 0) {
      bool z0 = p0 > 0.f, z1 = p1 > 0.f, z2 = p2 > 0.f, z3 = p3 > 0.f;
      flagb[j] = z0; flagb[j + 1] = z1; flagb[j + 2] = z2; flagb[j + 3] = z3;
      if (z0) atomicAdd(pos + s0, 1);
      if (z1) atomicAdd(pos + s1, 1);
      if (z2) atomicAdd(pos + s2, 1);
      if (z3) atomicAdd(pos + s3, 1);
    }
  }
  for (; j < je; ++j) {
    int s = csr_src[j];
    float4 hs = *(const float4*)(h + (size_t)s * D + c * 4);
    float p = fmaf(hs.x, hd.x, fmaf(hs.y, hd.y, fmaf(hs.z, hd.z, hs.w * hd.w)));
#pragma unroll
    for (int o = G / 2; o > 0; o >>= 1) p += __shfl_xor(p, o);
    if (c == 0) {
      bool pz = p > 0.f;
      flagb[j] = (unsigned char)pz;
      if (pz) atomicAdd(pos + s, 1);
    }
  }
}

// Fused denom + in-place scale: lane0 of each G-group computes dinv for its
// node from replicated pos + deg, broadcasts, group scales the h row.
template <int D>
__global__ void denom_scale_k(const int* __restrict__ pos_rep, const int* __restrict__ deg,
                              float* __restrict__ h, int N) {
  const int G = D / 4;
  int t = blockIdx.x * 256 + threadIdx.x;
  int node = t / G;
  int c = t & (G - 1);
  if (node >= N) return;
  float dinv = 0.f;
  if (c == 0) {
    int p = 0;
#pragma unroll
    for (int r = 0; r < REP; r++) p += pos_rep[r * N + node];
    int dg = deg[node];
    dinv = (p > 0) ? 1.f / ((float)p + (float)(dg - p) * EXPC)
                   : 1.f / (EXPC * (float)dg);
  }
  dinv = __shfl(dinv, 0, G);
  float4* hp = (float4*)(h + (size_t)node * D + c * 4);
  float4 v = *hp;
  v.x *= dinv; v.y *= dinv; v.z *= dinv; v.w *= dinv;
  *hp = v;
}

// Gather over CSR (h pre-scaled by dinv): weight is (flag?1:c). 4-edge unroll.
template <int D, bool FUSE_LSM>
__global__ void gather_csr_k(const int* __restrict__ csr_src, const int* __restrict__ off,
                             const int* __restrict__ indeg,
                             const unsigned char* __restrict__ flagb,
                             const float* __restrict__ h,
                             const float* __restrict__ b, float* __restrict__ outp, int N) {
  const int G = D / 4;
  int t = blockIdx.x * 256 + threadIdx.x;
  int node = t / G;
  int c = t & (G - 1);
  if (node >= N) return;
  float4 acc = *(const float4*)(b + c * 4);
  int j = off[node];
  int je = j + indeg[node];
  for (; j + 4 <= je; j += 4) {
    int s0 = csr_src[j], s1 = csr_src[j + 1], s2 = csr_src[j + 2], s3 = csr_src[j + 3];
    float w0 = flagb[j] ? 1.f : EXPC;
    float w1 = flagb[j + 1] ? 1.f : EXPC;
    float w2 = flagb[j + 2] ? 1.f : EXPC;
    float w3 = flagb[j + 3] ? 1.f : EXPC;
    float4 v0 = *(const float4*)(h + (size_t)s0 * D + c * 4);
    float4 v1 = *(const float4*)(h + (size_t)s1 * D + c * 4);
    float4 v2 = *(const float4*)(h + (size_t)s2 * D + c * 4);
    float4 v3 = *(const float4*)(h + (size_t)s3 * D + c * 4);
    acc.x = fmaf(w0, v0.x, fmaf(w1, v1.x, fmaf(w2, v2.x, fmaf(w3, v3.x, acc.x))));
    acc.y = fmaf(w0, v0.y, fmaf(w1, v1.y, fmaf(w2, v2.y, fmaf(w3, v3.y, acc.y))));
    acc.z = fmaf(w0, v0.z, fmaf(w1, v1.z, fmaf(w2, v2.z, fmaf(w3, v3.z, acc.z))));
    acc.w = fmaf(w0, v0.w, fmaf(w1, v1.w, fmaf(w2, v2.w, fmaf(w3, v3.w, acc.w))));
  }
  for (; j < je; ++j) {
    int s = csr_src[j];
    float w = flagb[j] ? 1.f : EXPC;
    float4 hv = *(const float4*)(h + (size_t)s * D + c * 4);
    acc.x = fmaf(w, hv.x, acc.x);
    acc.y = fmaf(w, hv.y, acc.y);
    acc.z = fmaf(w, hv.z, acc.z);
    acc.w = fmaf(w, hv.w, acc.w);
  }
  if (FUSE_LSM) {
    float m = fmaxf(fmaxf(acc.x, acc.y), fmaxf(acc.z, acc.w));
    m = fmaxf(m, __shfl_xor(m, 1));
    m = fmaxf(m, __shfl_xor(m, 2));
    float s = expf(acc.x - m) + expf(acc.y - m) + expf(acc.z - m) + expf(acc.w - m);
    s += __shfl_xor(s, 1);
    s += __shfl_xor(s, 2);
    float lse = m + logf(s);
    acc.x -= lse; acc.y -= lse; acc.z -= lse; acc.w -= lse;
  }
  *(float4*)(outp + (size_t)node * D + c * 4) = acc;
}

extern "C" void kernel_launch(void* const* d_in, const int* in_sizes, int n_in,
                              void* d_out, int out_size, void* d_ws, size_t ws_size,
                              hipStream_t stream) {
  const float* x = (const float*)d_in[0];
  const int* ei = (const int*)d_in[1];
  const float* W1 = (const float*)d_in[2];
  const float* b1 = (const float*)d_in[3];
  const float* W2 = (const float*)d_in[4];
  const float* b2 = (const float*)d_in[5];
  float* out = (float*)d_out;

  const int N = in_sizes[0] / 64;
  const int E = in_sizes[1] / 2;
  const int Et = E + N;
  const int B = 256;
  const int nbT = (N + 63) / 64;             // GEMM tiles
  const int NB = (N + 255) >> 8;             // coarse buckets (<=512)
  const int nbP = (Et + CHUNK - 1) / CHUNK;  // partition chunks

  // Workspace (~68 MB). part arrays dead after pass C/C' -> pos_rep/flagb alias.
  char* ws = (char*)d_ws;
  float* h1 = (float*)ws;    ws += (size_t)N * 64 * 4;   // 25.6 MB
  float* agg1 = (float*)ws;  ws += (size_t)N * 64 * 4;   // 25.6 MB
  int* deg = (int*)ws;       ws += (size_t)N * 4;
  int* in_deg = (int*)ws;    ws += (size_t)N * 4;
  int* off = (int*)ws;       ws += (size_t)N * 4;
  int* chd = (int*)ws;       ws += 512 * 4;
  int* chs = (int*)ws;       ws += 512 * 4;
  int* cbd = (int*)ws;       ws += 512 * 4;
  int* cbs = (int*)ws;       ws += 512 * 4;
  int* cud = (int*)ws;       ws += 512 * 4;
  int* cus = (int*)ws;       ws += 512 * 4;
  int* csr_src = (int*)ws;   ws += (size_t)Et * 4;       // 6.8 MB
  char* P = ws;              ws += (size_t)Et * 4 + (size_t)Et;  // 8.5 MB
  int* part_dst = (int*)P;
  unsigned char* part_src = (unsigned char*)(P + (size_t)Et * 4);
  int* pos_rep = (int*)P;                        // alias (after pass C/C')
  unsigned char* flagb = (unsigned char*)(P + (size_t)REP * N * 4);

  // ---- CSR structure (partition pipeline, data-independent) ----
  hipLaunchKernelGGL(zero_i32, dim3(4), dim3(B), 0, stream, chd, 1024);  // chd+chs
  hipLaunchKernelGGL(passA_k, dim3(nbP), dim3(B), 0, stream, ei, chd, chs, E, Et);
  hipLaunchKernelGGL(scan2_k, dim3(1), dim3(512), 0, stream, chd, chs, cbd, cbs, cud, cus, NB);
  hipLaunchKernelGGL(passB_k, dim3(nbP), dim3(B), 0, stream, ei, cud, cus,
                     part_dst, part_src, E, Et);
  hipLaunchKernelGGL(passC_k, dim3(NB), dim3(B), 0, stream, part_dst, cbd, chd,
                     csr_src, in_deg, off, N);
  hipLaunchKernelGGL(passCs_k, dim3(NB), dim3(B), 0, stream, part_src, cbs, chs, deg, N);

  // ---- layer 1 (D=64) ----
  hipLaunchKernelGGL((gemm64_k<false>), dim3(nbT), dim3(B), 0, stream, x, W1, h1, N);
  hipLaunchKernelGGL(zero_i32, dim3((REP * N + B - 1) / B), dim3(B), 0, stream,
                     pos_rep, REP * N);
  hipLaunchKernelGGL((alpha_csr_k<64>), dim3(((size_t)N * 16 + B - 1) / B), dim3(B), 0,
                     stream, csr_src, off, in_deg, h1, flagb, pos_rep, N);
  hipLaunchKernelGGL((denom_scale_k<64>), dim3(((size_t)N * 16 + B - 1) / B), dim3(B), 0,
                     stream, pos_rep, deg, h1, N);
  hipLaunchKernelGGL((gather_csr_k<64, false>), dim3(((size_t)N * 16 + B - 1) / B), dim3(B),
                     0, stream, csr_src, off, in_deg, flagb, h1, b1, agg1, N);

  // ---- layer 2 (D=16): relu folded into gemm load, log-softmax fused ----
  float* h2 = h1;  // alias: h1 dead once gather1 completes
  hipLaunchKernelGGL((gemm16_k<true>), dim3(nbT), dim3(B), 0, stream, agg1, W2, h2, N);
  hipLaunchKernelGGL(zero_i32, dim3((REP * N + B - 1) / B), dim3(B), 0, stream,
                     pos_rep, REP * N);
  hipLaunchKernelGGL((alpha_csr_k<16>), dim3(((size_t)N * 4 + B - 1) / B), dim3(B), 0,
                     stream, csr_src, off, in_deg, h2, flagb, pos_rep, N);
  hipLaunchKernelGGL((denom_scale_k<16>), dim3(((size_t)N * 4 + B - 1) / B), dim3(B), 0,
                     stream, pos_rep, deg, h2, N);
  hipLaunchKernelGGL((gather_csr_k<16, true>), dim3(((size_t)N * 4 + B - 1) / B), dim3(B),
                     0, stream, csr_src, off, in_deg, flagb, h2, b2, out, N);
}